// Round 11
// baseline (310.910 us; speedup 1.0000x reference)
//
#include <hip/hip_runtime.h>
#include <hip/hip_bf16.h>
#include <hip/hip_cooperative_groups.h>
#include <math.h>

namespace cg = cooperative_groups;

// ---------------------------------------------------------------------------
// GCN 2-layer forward. Pipeline (round 11):
//   build_kernel (COOPERATIVE, fuses: hist -> col_scan -> base_scan ->
//   scatter (LDS counting sort, coalesced flush) -> bucket_csr) ->
//   gemm1 (MFMA bf16, fp8 out, nontemporal x stream) ->
//   agg1 (16-lane group per node, fp8 gather + fused gemm2) -> agg2 (+softmax)
// Round-10 evidence: all user kernels <57us; build pipeline ~65us + ~20us of
// launch gaps is the largest aggregate cost. Fusing 5 launches -> 1 coop
// kernel removes 4 gaps; hist gets 512 thr. Fallback to separate kernels if
// cooperative launch is refused (same stream, deterministic).
// ---------------------------------------------------------------------------

#define NB 256       // build blocks (hist & scatter slices)
#define MAXB 512     // max buckets (n <= 131072)
#define SCHUNK 12544 // scatter LDS entries (>= ceil(E/NB) for E<=3.21M)

typedef __attribute__((ext_vector_type(8))) short bf16x8;
typedef __attribute__((ext_vector_type(4))) float f32x4;
typedef __attribute__((ext_vector_type(2))) float f32x2;
typedef __attribute__((ext_vector_type(4))) float nf4;

__device__ __forceinline__ int edge_val(const void* ep, size_t idx, int is64) {
    if (is64) return (int)(((const long long*)ep)[idx]);
    return ((const int*)ep)[idx];
}

// int64 vs int32 edge buffer: high words of first 64 entries all zero only
// for int64 (node ids < 1e5). Per-wave ballot; all waves agree.
__device__ __forceinline__ int detect64(const unsigned int* __restrict__ ew, int E) {
    const int lane = (int)(threadIdx.x & 63);
    const int idx = (lane < E) ? (2 * lane + 1) : 1;
    const unsigned long long m = __ballot(ew[idx] != 0u);
    return m == 0ull ? 1 : 0;
}

__device__ __forceinline__ unsigned short f2bf(float f) {  // RNE
    unsigned int u = __float_as_uint(f);
    return (unsigned short)((u + 0x7FFFu + ((u >> 16) & 1u)) >> 16);
}

// fp8 e4m3 (OCP) decode of a 4-byte group via HW cvt
__device__ __forceinline__ void acc_fp8row(unsigned int r, float& a0, float& a1,
                                           float& a2, float& a3) {
    const f32x2 lo = __builtin_amdgcn_cvt_pk_f32_fp8((int)r, false);
    const f32x2 hi = __builtin_amdgcn_cvt_pk_f32_fp8((int)r, true);
    a0 += lo[0]; a1 += lo[1]; a2 += hi[0]; a3 += hi[1];
}

__device__ __forceinline__ unsigned char f32_to_fp8(float f) {
    const int enc = __builtin_amdgcn_cvt_pk_fp8_f32(f, 0.f, 0, false);
    return (unsigned char)(enc & 0xff);
}

// ===================== fused cooperative CSR build =====================
// P1 hist -> P2 col scans -> P3 base scan -> P4 scatter -> P5 bucket csr
__global__ __launch_bounds__(512, 1) void build_kernel(
    const void* __restrict__ edges, int E, int* __restrict__ ghist,
    int* __restrict__ goff, int* __restrict__ bsum, int* __restrict__ bbase,
    int* __restrict__ row_ptr, float* __restrict__ dinv,
    int* __restrict__ col_src, unsigned int* __restrict__ ebuf, int n, int B) {
    cg::grid_group grid = cg::this_grid();
    __shared__ unsigned int buf[SCHUNK];
    __shared__ int sm[MAXB];
    __shared__ int lb[MAXB];
    __shared__ int lf[MAXB];
    const int tid = threadIdx.x;
    const int blk = blockIdx.x;
    const int is64 = detect64((const unsigned int*)edges, E);
    const int per = (E + NB - 1) / NB;
    const int s0 = blk * per;
    const int s1 = min(s0 + per, E);

    // ---- P1: per-block histogram of dst buckets (hist in lf) ----
    for (int i = tid; i < B; i += 512) lf[i] = 0;
    __syncthreads();
    for (int i = s0 + tid; i < s1; i += 512) {
        const int d = edge_val(edges, (size_t)E + i, is64);
        atomicAdd(&lf[d >> 8], 1);
    }
    __syncthreads();
    for (int i = tid; i < B; i += 512) ghist[(size_t)blk * B + i] = lf[i];
    grid.sync();

    // ---- P2: column scans. Block j scans bucket-columns j and j+256.
    {
        const int col = blk + ((tid >> 8) << 8);  // blk or blk+256
        const int t = tid & 255;                  // block-row index
        const bool act = col < B;
        const int v = act ? ghist[(size_t)t * B + col] : 0;
        sm[tid] = v;
        __syncthreads();
        for (int off = 1; off < 256; off <<= 1) {
            const int val = (t >= off) ? sm[tid - off] : 0;
            __syncthreads();
            sm[tid] += val;
            __syncthreads();
        }
        if (act) {
            goff[(size_t)t * B + col] = sm[tid] - v;
            if (t == 255) bsum[col] = sm[tid];
        }
    }
    grid.sync();

    // ---- P3: bucket-base exclusive scan (block 0) ----
    if (blk == 0) {
        const int v = (tid < B) ? bsum[tid] : 0;
        sm[tid] = v;
        __syncthreads();
        for (int off = 1; off < 512; off <<= 1) {
            const int val = (tid >= off) ? sm[tid - off] : 0;
            __syncthreads();
            sm[tid] += val;
            __syncthreads();
        }
        if (tid < B) bbase[tid] = sm[tid] - v;
        if (tid == 0) { bbase[B] = E; row_ptr[n] = E; }
    }
    grid.sync();

    // ---- P4: scatter (LDS counting sort by bucket, coalesced run flush) ----
    if (per <= SCHUNK) {
        const int c = (tid < B) ? ghist[(size_t)blk * B + tid] : 0;
        sm[tid] = c;
        __syncthreads();
        for (int off = 1; off < MAXB; off <<= 1) {
            const int val = (tid >= off) ? sm[tid - off] : 0;
            __syncthreads();
            sm[tid] += val;
            __syncthreads();
        }
        if (tid < B) { lb[tid] = sm[tid] - c; lf[tid] = sm[tid] - c; }
        __syncthreads();
        for (int i = s0 + tid; i < s1; i += 512) {
            const int d = edge_val(edges, (size_t)E + i, is64);
            const int s = edge_val(edges, (size_t)i, is64);
            const unsigned int val = ((unsigned int)s << 8) | (unsigned int)(d & 255);
            const int pos = atomicAdd(&lf[d >> 8], 1);
            buf[pos] = val;
        }
        __syncthreads();
        const int lane = tid & 63;
        const int wv = tid >> 6;
        for (int b = wv; b < B; b += 8) {
            const int lo = lb[b];
            const int cnt = lf[b] - lo;
            if (cnt > 0) {
                unsigned int* dst = ebuf + bbase[b] + goff[(size_t)blk * B + b];
                for (int k = lane; k < cnt; k += 64) dst[k] = buf[lo + k];
            }
        }
    } else {  // adversarial-size fallback: direct scatter
        for (int i = tid; i < B; i += 512)
            lf[i] = bbase[i] + goff[(size_t)blk * B + i];
        __syncthreads();
        for (int i = s0 + tid; i < s1; i += 512) {
            const int d = edge_val(edges, (size_t)E + i, is64);
            const int s = edge_val(edges, (size_t)i, is64);
            const int pos = atomicAdd(&lf[d >> 8], 1);
            ebuf[pos] = ((unsigned int)s << 8) | (unsigned int)(d & 255);
        }
    }
    grid.sync();

    // ---- P5: per-bucket counting sort -> col_src + row_ptr + dinv ----
    // hist->sm, scn->lb, fill->lf (first 256 entries each)
    for (int bb = blk; bb < B; bb += NB) {
        __syncthreads();
        if (tid < 256) sm[tid] = 0;
        __syncthreads();
        const int base = bbase[bb];
        const int m = bbase[bb + 1] - base;
        const unsigned int* eb = ebuf + base;
        for (int i = tid; i < m; i += 512) atomicAdd(&sm[eb[i] & 255u], 1);
        __syncthreads();
        if (tid < 256) lb[tid] = sm[tid];
        __syncthreads();
        for (int off = 1; off < 256; off <<= 1) {
            int val = 0;
            if (tid < 256 && tid >= off) val = lb[tid - off];
            __syncthreads();
            if (tid < 256) lb[tid] += val;
            __syncthreads();
        }
        if (tid < 256) {
            const int excl = lb[tid] - sm[tid];
            lf[tid] = excl;
            const int v = bb * 256 + tid;
            if (v < n) {
                row_ptr[v] = base + excl;
                dinv[v] = rsqrtf((float)sm[tid] + 1.0f);
            }
        }
        __syncthreads();
        for (int i = tid; i < m; i += 512) {
            const unsigned int e = eb[i];
            const int p = atomicAdd(&lf[e & 255u], 1);
            col_src[base + p] = (int)(e >> 8);
        }
    }
}

// ===================== fallback (round-10) build kernels =====================
__global__ __launch_bounds__(256) void hist_pass(
    const void* __restrict__ edges, int E, int* __restrict__ ghist, int B) {
    __shared__ int hist[MAXB];
    const int tid = threadIdx.x;
    for (int i = tid; i < B; i += 256) hist[i] = 0;
    const int is64 = detect64((const unsigned int*)edges, E);
    __syncthreads();
    const int per = (E + NB - 1) / NB;
    const int s0 = blockIdx.x * per;
    const int s1 = min(s0 + per, E);
    for (int i = s0 + tid; i < s1; i += 256) {
        const int d = edge_val(edges, (size_t)E + i, is64);
        atomicAdd(&hist[d >> 8], 1);
    }
    __syncthreads();
    for (int i = tid; i < B; i += 256) ghist[(size_t)blockIdx.x * B + i] = hist[i];
}

__global__ __launch_bounds__(NB) void col_scan(
    const int* __restrict__ ghist, int* __restrict__ goff,
    int* __restrict__ bsum, int B) {
    __shared__ int sm[NB];
    const int tid = threadIdx.x;
    const int b = blockIdx.x;
    const int v = ghist[(size_t)tid * B + b];
    sm[tid] = v;
    __syncthreads();
    for (int off = 1; off < NB; off <<= 1) {
        int val = (tid >= off) ? sm[tid - off] : 0;
        __syncthreads();
        sm[tid] += val;
        __syncthreads();
    }
    goff[(size_t)tid * B + b] = sm[tid] - v;
    if (tid == NB - 1) bsum[b] = sm[tid];
}

__global__ __launch_bounds__(512) void base_scan(
    const int* __restrict__ bsum, int* __restrict__ bbase,
    int* __restrict__ row_ptr, int B, int n, int E) {
    __shared__ int sm[512];
    const int tid = threadIdx.x;
    const int v = (tid < B) ? bsum[tid] : 0;
    sm[tid] = v;
    __syncthreads();
    for (int off = 1; off < 512; off <<= 1) {
        int val = (tid >= off) ? sm[tid - off] : 0;
        __syncthreads();
        sm[tid] += val;
        __syncthreads();
    }
    if (tid < B) bbase[tid] = sm[tid] - v;
    if (tid == 0) { bbase[B] = E; row_ptr[n] = E; }
}

__global__ __launch_bounds__(512) void scatter_pass(
    const void* __restrict__ edges, int E,
    const int* __restrict__ ghist, const int* __restrict__ goff,
    const int* __restrict__ bbase, unsigned int* __restrict__ ebuf, int B) {
    __shared__ unsigned int buf[SCHUNK];
    __shared__ int lb[MAXB];
    __shared__ int lf[MAXB];
    __shared__ int sm[MAXB];
    const int tid = threadIdx.x;
    const int blk = blockIdx.x;
    const int is64 = detect64((const unsigned int*)edges, E);
    const int per = (E + NB - 1) / NB;
    const int s0 = blk * per;
    const int s1 = min(s0 + per, E);
    if (per <= SCHUNK) {
        const int c = (tid < B) ? ghist[(size_t)blk * B + tid] : 0;
        sm[tid] = c;
        __syncthreads();
        for (int off = 1; off < MAXB; off <<= 1) {
            int val = (tid >= off) ? sm[tid - off] : 0;
            __syncthreads();
            sm[tid] += val;
            __syncthreads();
        }
        if (tid < B) { lb[tid] = sm[tid] - c; lf[tid] = sm[tid] - c; }
        __syncthreads();
        for (int i = s0 + tid; i < s1; i += 512) {
            const int d = edge_val(edges, (size_t)E + i, is64);
            const int s = edge_val(edges, (size_t)i, is64);
            const unsigned int val = ((unsigned int)s << 8) | (unsigned int)(d & 255);
            const int pos = atomicAdd(&lf[d >> 8], 1);
            buf[pos] = val;
        }
        __syncthreads();
        const int lane = tid & 63;
        const int wv = tid >> 6;
        for (int b = wv; b < B; b += 8) {
            const int lo = lb[b];
            const int cnt = lf[b] - lo;
            if (cnt > 0) {
                unsigned int* dst = ebuf + bbase[b] + goff[(size_t)blk * B + b];
                for (int k = lane; k < cnt; k += 64) dst[k] = buf[lo + k];
            }
        }
    } else {
        for (int i = tid; i < B; i += 512)
            lf[i] = bbase[i] + goff[(size_t)blk * B + i];
        __syncthreads();
        for (int i = s0 + tid; i < s1; i += 512) {
            const int d = edge_val(edges, (size_t)E + i, is64);
            const int s = edge_val(edges, (size_t)i, is64);
            const int pos = atomicAdd(&lf[d >> 8], 1);
            ebuf[pos] = ((unsigned int)s << 8) | (unsigned int)(d & 255);
        }
    }
}

__global__ __launch_bounds__(512) void bucket_csr(
    const unsigned int* __restrict__ ebuf, const int* __restrict__ bbase,
    int* __restrict__ row_ptr, float* __restrict__ dinv,
    int* __restrict__ col_src, int n) {
    __shared__ int hist[256];
    __shared__ int scn[256];
    __shared__ int fill[256];
    const int tid = threadIdx.x;
    const int b = blockIdx.x;
    if (tid < 256) hist[tid] = 0;
    __syncthreads();
    const int base = bbase[b];
    const int m = bbase[b + 1] - base;
    const unsigned int* eb = ebuf + base;
    for (int i = tid; i < m; i += 512) atomicAdd(&hist[eb[i] & 255u], 1);
    __syncthreads();
    if (tid < 256) scn[tid] = hist[tid];
    __syncthreads();
    for (int off = 1; off < 256; off <<= 1) {
        int val = 0;
        if (tid < 256 && tid >= off) val = scn[tid - off];
        __syncthreads();
        if (tid < 256) scn[tid] += val;
        __syncthreads();
    }
    if (tid < 256) {
        const int excl = scn[tid] - hist[tid];
        fill[tid] = excl;
        const int v = b * 256 + tid;
        if (v < n) {
            row_ptr[v] = base + excl;
            dinv[v] = rsqrtf((float)hist[tid] + 1.0f);
        }
    }
    __syncthreads();
    for (int i = tid; i < m; i += 512) {
        const unsigned int e = eb[i];
        const int p = atomicAdd(&fill[e & 255u], 1);
        col_src[base + p] = (int)(e >> 8);
    }
}

// ===================== compute kernels (round-10, proven) =====================
// GEMM1 (MFMA): hs1f8[v][c] = fp8((x@W1)[v][c] * dinv[v]),  256 -> 64.
__global__ __launch_bounds__(256) void gemm1_kernel(
    const float* __restrict__ x, const float* __restrict__ W1,
    const float* __restrict__ dinv, unsigned char* __restrict__ hs1f8, int n) {
    __shared__ unsigned short wt[64 * 264];  // [col][k], 33792 B
    const int tid = threadIdx.x;
    for (int i = tid; i < 4096; i += 256) {
        const int k = i >> 4;
        const int c0 = (i & 15) * 4;
        const float4 w = *((const float4*)W1 + i);
        wt[(c0 + 0) * 264 + k] = f2bf(w.x);
        wt[(c0 + 1) * 264 + k] = f2bf(w.y);
        wt[(c0 + 2) * 264 + k] = f2bf(w.z);
        wt[(c0 + 3) * 264 + k] = f2bf(w.w);
    }
    __syncthreads();

    const int lane = tid & 63;
    const int wid = tid >> 6;
    const int row0 = blockIdx.x * 64 + wid * 16;
    const int rr = lane & 15;
    const int kh = lane >> 4;

    union FragU { bf16x8 v; unsigned short u[8]; };
    bf16x8 af[8];
    {
        int r = row0 + rr;
        if (r >= n) r = n - 1;
        const float* xr = x + (size_t)r * 256 + kh * 8;
#pragma unroll
        for (int ks = 0; ks < 8; ++ks) {
            const nf4 p0 = __builtin_nontemporal_load((const nf4*)(xr + ks * 32));
            const nf4 p1 = __builtin_nontemporal_load((const nf4*)(xr + ks * 32 + 4));
            FragU f;
            f.u[0] = f2bf(p0[0]); f.u[1] = f2bf(p0[1]);
            f.u[2] = f2bf(p0[2]); f.u[3] = f2bf(p0[3]);
            f.u[4] = f2bf(p1[0]); f.u[5] = f2bf(p1[1]);
            f.u[6] = f2bf(p1[2]); f.u[7] = f2bf(p1[3]);
            af[ks] = f.v;
        }
    }
    f32x4 acc[4];
#pragma unroll
    for (int ct = 0; ct < 4; ++ct) acc[ct] = (f32x4){0.f, 0.f, 0.f, 0.f};
#pragma unroll
    for (int ct = 0; ct < 4; ++ct) {
        const unsigned short* wcol = wt + (ct * 16 + rr) * 264 + kh * 8;
#pragma unroll
        for (int ks = 0; ks < 8; ++ks) {
            const bf16x8 bf = *(const bf16x8*)(wcol + ks * 32);
            acc[ct] = __builtin_amdgcn_mfma_f32_16x16x32_bf16(af[ks], bf, acc[ct], 0, 0, 0);
        }
    }
#pragma unroll
    for (int j = 0; j < 4; ++j) {
        const int gr = row0 + kh * 4 + j;
        if (gr < n) {
            const float dv = dinv[gr];
#pragma unroll
            for (int ct = 0; ct < 4; ++ct)
                hs1f8[(size_t)gr * 64 + ct * 16 + rr] = f32_to_fp8(acc[ct][j] * dv);
        }
    }
}

// AGG1 + fused GEMM2: 16-lane group per node (4 nodes/wave).
__global__ __launch_bounds__(256) void agg1_kernel(
    const int* __restrict__ row_ptr, const int* __restrict__ col_src,
    const unsigned char* __restrict__ hs1f8, const float* __restrict__ dinv,
    const float* __restrict__ b1, const float* __restrict__ W2,
    float* __restrict__ hs2, int n) {
    const int tid = threadIdx.x;
    const int q = tid & 15;
    const int v = blockIdx.x * 16 + (tid >> 4);
    if (v >= n) return;
    const int rs = row_ptr[v];
    const int re = row_ptr[v + 1];
    float a0 = 0.f, a1 = 0.f, a2 = 0.f, a3 = 0.f;
    int e = rs;
    for (; e + 16 <= re; e += 16) {
        const int cs = col_src[e + q];
        unsigned int r[16];
#pragma unroll
        for (int j = 0; j < 16; ++j) {
            const int s = __shfl(cs, j, 16);
            r[j] = *(const unsigned int*)(hs1f8 + (size_t)s * 64 + q * 4);
        }
#pragma unroll
        for (int j = 0; j < 16; ++j) acc_fp8row(r[j], a0, a1, a2, a3);
    }
    const int rem = re - e;
    if (rem > 0) {
        const int cs = col_src[(q < rem) ? e + q : re - 1];
        for (int j = 0; j < rem; ++j) {
            const int s = __shfl(cs, j, 16);
            const unsigned int r = *(const unsigned int*)(hs1f8 + (size_t)s * 64 + q * 4);
            acc_fp8row(r, a0, a1, a2, a3);
        }
    }
    float s0 = 0.f, s1 = 0.f, s2 = 0.f, s3 = 0.f;
    acc_fp8row(*(const unsigned int*)(hs1f8 + (size_t)v * 64 + q * 4), s0, s1, s2, s3);
    const float dv = dinv[v];
    const float4 bb = ((const float4*)b1)[q];
    float4 res;
    res.x = dv * (a0 + s0) + bb.x;
    res.y = dv * (a1 + s1) + bb.y;
    res.z = dv * (a2 + s2) + bb.z;
    res.w = dv * (a3 + s3) + bb.w;
    res.x = res.x > 0.f ? res.x : 0.01f * res.x;
    res.y = res.y > 0.f ? res.y : 0.01f * res.y;
    res.z = res.z > 0.f ? res.z : 0.01f * res.z;
    res.w = res.w > 0.f ? res.w : 0.01f * res.w;
    const float4* W2v = (const float4*)W2;
    const float4 w0 = W2v[q * 4 + 0], w1 = W2v[q * 4 + 1];
    const float4 w2 = W2v[q * 4 + 2], w3 = W2v[q * 4 + 3];
    float4 p;
    p.x = res.x * w0.x + res.y * w1.x + res.z * w2.x + res.w * w3.x;
    p.y = res.x * w0.y + res.y * w1.y + res.z * w2.y + res.w * w3.y;
    p.z = res.x * w0.z + res.y * w1.z + res.z * w2.z + res.w * w3.z;
    p.w = res.x * w0.w + res.y * w1.w + res.z * w2.w + res.w * w3.w;
#pragma unroll
    for (int s = 1; s < 16; s <<= 1) {
        p.x += __shfl_xor(p.x, s, 16); p.y += __shfl_xor(p.y, s, 16);
        p.z += __shfl_xor(p.z, s, 16); p.w += __shfl_xor(p.w, s, 16);
    }
    if (q == 0) {
        float4 o; o.x = p.x * dv; o.y = p.y * dv; o.z = p.z * dv; o.w = p.w * dv;
        *(float4*)(hs2 + (size_t)v * 4) = o;
    }
}

// AGG2 + softmax: wave per node; lane -> (edge slot = lane>>2, col = lane&3)
__global__ __launch_bounds__(256) void agg2_kernel(
    const int* __restrict__ row_ptr, const int* __restrict__ col_src,
    const float* __restrict__ hs2, const float* __restrict__ dinv,
    const float* __restrict__ b2, float* __restrict__ out, int n) {
    const int lane = threadIdx.x & 63;
    int v = blockIdx.x * 4 + (threadIdx.x >> 6);
    v = __builtin_amdgcn_readfirstlane(v);
    if (v >= n) return;
    const int c = lane & 3;
    const int ei = lane >> 2;
    const int rs = row_ptr[v];
    const int re = row_ptr[v + 1];
    float acc = 0.f;
    for (int e0 = rs; e0 < re; e0 += 16) {
        const int e = e0 + ei;
        if (e < re) {
            const int s = col_src[e];
            acc += hs2[(size_t)s * 4 + c];
        }
    }
    acc += __shfl_xor(acc, 4);
    acc += __shfl_xor(acc, 8);
    acc += __shfl_xor(acc, 16);
    acc += __shfl_xor(acc, 32);
    const float val = dinv[v] * (acc + hs2[(size_t)v * 4 + c]) + b2[c];
    float m = fmaxf(val, __shfl_xor(val, 1));
    m = fmaxf(m, __shfl_xor(m, 2));
    const float ex = __expf(val - m);
    float s = ex + __shfl_xor(ex, 1);
    s += __shfl_xor(s, 2);
    if (lane < 4) out[(size_t)v * 4 + c] = ex / s;
}

extern "C" void kernel_launch(void* const* d_in, const int* in_sizes, int n_in,
                              void* d_out, int out_size, void* d_ws, size_t ws_size,
                              hipStream_t stream) {
    const float* x  = (const float*)d_in[0];
    const void*  ei = d_in[1];
    const float* W1 = (const float*)d_in[2];
    const float* b1 = (const float*)d_in[3];
    const float* W2 = (const float*)d_in[4];
    const float* b2 = (const float*)d_in[5];
    int n = in_sizes[0] / 256;
    int E = in_sizes[1] / 2;
    int B = (n + 255) / 256;  // <= MAXB for n <= 131072

    char* ws = (char*)d_ws;
    size_t off = 0;
    auto alloc = [&](size_t bytes) -> void* {
        void* p = ws + off;
        off += (bytes + 255) & ~(size_t)255;
        return p;
    };
    int*   ghist   = (int*)alloc(sizeof(int) * (size_t)NB * B);
    int*   goff    = (int*)alloc(sizeof(int) * (size_t)NB * B);
    int*   bsum    = (int*)alloc(sizeof(int) * B);
    int*   bbase   = (int*)alloc(sizeof(int) * (B + 1));
    int*   row_ptr = (int*)alloc(sizeof(int) * (n + 1));
    int*   col_src = (int*)alloc(sizeof(int) * (size_t)E);
    float* dinv    = (float*)alloc(sizeof(float) * n);
    unsigned char* hs1f8 = (unsigned char*)alloc(sizeof(unsigned char) * (size_t)n * 64);
    float* hs2     = (float*)alloc(sizeof(float) * (size_t)n * 4);
    unsigned int* ebuf = (unsigned int*)alloc(sizeof(unsigned int) * (size_t)E);
    (void)n_in; (void)out_size; (void)ws_size;

    // fused cooperative build; fall back to 5-kernel path if refused
    void* args[] = {(void*)&ei, (void*)&E, (void*)&ghist, (void*)&goff,
                    (void*)&bsum, (void*)&bbase, (void*)&row_ptr, (void*)&dinv,
                    (void*)&col_src, (void*)&ebuf, (void*)&n, (void*)&B};
    hipError_t cerr = hipLaunchCooperativeKernel((void*)build_kernel, dim3(NB),
                                                 dim3(512), args, 0, stream);
    if (cerr != hipSuccess) {
        (void)hipGetLastError();  // clear sticky error
        hist_pass<<<NB, 256, 0, stream>>>(ei, E, ghist, B);
        col_scan<<<B, NB, 0, stream>>>(ghist, goff, bsum, B);
        base_scan<<<1, 512, 0, stream>>>(bsum, bbase, row_ptr, B, n, E);
        scatter_pass<<<NB, 512, 0, stream>>>(ei, E, ghist, goff, bbase, ebuf, B);
        bucket_csr<<<B, 512, 0, stream>>>(ebuf, bbase, row_ptr, dinv, col_src, n);
    }
    gemm1_kernel<<<(n + 63) / 64, 256, 0, stream>>>(x, W1, dinv, hs1f8, n);
    agg1_kernel<<<(n + 15) / 16, 256, 0, stream>>>(row_ptr, col_src, hs1f8, dinv, b1, W2, hs2, n);
    agg2_kernel<<<(n + 3) / 4, 256, 0, stream>>>(row_ptr, col_src, hs2, dinv, b2, (float*)d_out, n);
}

// Round 12
// 181.581 us; speedup vs baseline: 1.7122x; 1.7122x over previous
//
#include <hip/hip_runtime.h>
#include <hip/hip_bf16.h>
#include <math.h>

// ---------------------------------------------------------------------------
// GCN 2-layer forward. Pipeline (round 12 = round 10 + base_scan folded into
// scatter_pass + 512-thr hist):
//   hist_pass -> col_scan -> scatter_pass (computes bbase in-LDS, LDS
//   counting sort, coalesced flush) -> bucket_csr (-> CSR + dinv) ->
//   gemm1 (MFMA bf16, fp8 out, nontemporal x stream) ->
//   agg1 (16-lane group per node, fp8 gather + fused gemm2) -> agg2 (+softmax)
// Round-11 lesson: cooperative fusion of the build = 190us alone (1 blk/CU
// occupancy imposed on every phase). Round-9 lesson: split-phase agg1 also
// regressed. Structure is local-optimal; only strictly-local deltas remain.
// ---------------------------------------------------------------------------

#define NB 256       // build blocks (hist & scatter slices)
#define MAXB 512     // max buckets (n <= 131072)
#define SCHUNK 12544 // scatter LDS entries (>= ceil(E/NB) for E<=3.21M)

typedef __attribute__((ext_vector_type(8))) short bf16x8;
typedef __attribute__((ext_vector_type(4))) float f32x4;
typedef __attribute__((ext_vector_type(2))) float f32x2;
typedef __attribute__((ext_vector_type(4))) float nf4;

__device__ __forceinline__ int edge_val(const void* ep, size_t idx, int is64) {
    if (is64) return (int)(((const long long*)ep)[idx]);
    return ((const int*)ep)[idx];
}

// int64 vs int32 edge buffer: high words of first 64 entries all zero only
// for int64 (node ids < 1e5). Per-wave ballot; all waves agree.
__device__ __forceinline__ int detect64(const unsigned int* __restrict__ ew, int E) {
    const int lane = (int)(threadIdx.x & 63);
    const int idx = (lane < E) ? (2 * lane + 1) : 1;
    const unsigned long long m = __ballot(ew[idx] != 0u);
    return m == 0ull ? 1 : 0;
}

__device__ __forceinline__ unsigned short f2bf(float f) {  // RNE
    unsigned int u = __float_as_uint(f);
    return (unsigned short)((u + 0x7FFFu + ((u >> 16) & 1u)) >> 16);
}

// fp8 e4m3 (OCP) decode of a 4-byte group via HW cvt
__device__ __forceinline__ void acc_fp8row(unsigned int r, float& a0, float& a1,
                                           float& a2, float& a3) {
    const f32x2 lo = __builtin_amdgcn_cvt_pk_f32_fp8((int)r, false);
    const f32x2 hi = __builtin_amdgcn_cvt_pk_f32_fp8((int)r, true);
    a0 += lo[0]; a1 += lo[1]; a2 += hi[0]; a3 += hi[1];
}

__device__ __forceinline__ unsigned char f32_to_fp8(float f) {
    const int enc = __builtin_amdgcn_cvt_pk_fp8_f32(f, 0.f, 0, false);
    return (unsigned char)(enc & 0xff);
}

// Pass A: per-block histogram of dst buckets (512 threads).
__global__ __launch_bounds__(512) void hist_pass(
    const void* __restrict__ edges, int E, int* __restrict__ ghist, int B) {
    __shared__ int hist[MAXB];
    const int tid = threadIdx.x;
    for (int i = tid; i < B; i += 512) hist[i] = 0;
    const int is64 = detect64((const unsigned int*)edges, E);
    __syncthreads();
    const int per = (E + NB - 1) / NB;
    const int s0 = blockIdx.x * per;
    const int s1 = min(s0 + per, E);
    for (int i = s0 + tid; i < s1; i += 512) {
        const int d = edge_val(edges, (size_t)E + i, is64);
        atomicAdd(&hist[d >> 8], 1);
    }
    __syncthreads();
    for (int i = tid; i < B; i += 512) ghist[(size_t)blockIdx.x * B + i] = hist[i];
}

// Column scan: for bucket b, exclusive scan of ghist[blk][b] over blk.
__global__ __launch_bounds__(NB) void col_scan(
    const int* __restrict__ ghist, int* __restrict__ goff,
    int* __restrict__ bsum, int B) {
    __shared__ int sm[NB];
    const int tid = threadIdx.x;
    const int b = blockIdx.x;
    const int v = ghist[(size_t)tid * B + b];
    sm[tid] = v;
    __syncthreads();
    for (int off = 1; off < NB; off <<= 1) {
        int val = (tid >= off) ? sm[tid - off] : 0;
        __syncthreads();
        sm[tid] += val;
        __syncthreads();
    }
    goff[(size_t)tid * B + b] = sm[tid] - v;
    if (tid == NB - 1) bsum[b] = sm[tid];
}

// Pass B: scatter. Each block first derives bbase from bsum via LDS scan
// (redundant per block; block 0 persists it for bucket_csr), then LDS
// counting sort by bucket + coalesced run flush.
__global__ __launch_bounds__(512) void scatter_pass(
    const void* __restrict__ edges, int E,
    const int* __restrict__ ghist, const int* __restrict__ goff,
    const int* __restrict__ bsum, int* __restrict__ bbase_out,
    int* __restrict__ row_ptr, unsigned int* __restrict__ ebuf, int n, int B) {
    __shared__ unsigned int buf[SCHUNK];
    __shared__ int lb[MAXB];
    __shared__ int lf[MAXB];
    __shared__ int sm[MAXB];
    __shared__ int bb[MAXB + 1];
    const int tid = threadIdx.x;
    const int blk = blockIdx.x;
    const int is64 = detect64((const unsigned int*)edges, E);
    const int per = (E + NB - 1) / NB;
    const int s0 = blk * per;
    const int s1 = min(s0 + per, E);

    // bbase = exclusive scan of bsum (every block computes it)
    {
        const int v = (tid < B) ? bsum[tid] : 0;
        sm[tid] = v;
        __syncthreads();
        for (int off = 1; off < MAXB; off <<= 1) {
            const int val = (tid >= off) ? sm[tid - off] : 0;
            __syncthreads();
            sm[tid] += val;
            __syncthreads();
        }
        if (tid < B) bb[tid] = sm[tid] - v;
        if (tid == 0) bb[B] = E;
        if (blk == 0) {
            if (tid < B) bbase_out[tid] = bb[tid];
            if (tid == 0) { bbase_out[B] = E; row_ptr[n] = E; }
        }
    }
    __syncthreads();

    if (per <= SCHUNK) {
        const int c = (tid < B) ? ghist[(size_t)blk * B + tid] : 0;
        sm[tid] = c;
        __syncthreads();
        for (int off = 1; off < MAXB; off <<= 1) {
            const int val = (tid >= off) ? sm[tid - off] : 0;
            __syncthreads();
            sm[tid] += val;
            __syncthreads();
        }
        if (tid < B) { lb[tid] = sm[tid] - c; lf[tid] = sm[tid] - c; }
        __syncthreads();
        for (int i = s0 + tid; i < s1; i += 512) {
            const int d = edge_val(edges, (size_t)E + i, is64);
            const int s = edge_val(edges, (size_t)i, is64);
            const unsigned int val = ((unsigned int)s << 8) | (unsigned int)(d & 255);
            const int pos = atomicAdd(&lf[d >> 8], 1);
            buf[pos] = val;
        }
        __syncthreads();
        const int lane = tid & 63;
        const int wv = tid >> 6;
        for (int b = wv; b < B; b += 8) {
            const int lo = lb[b];
            const int cnt = lf[b] - lo;
            if (cnt > 0) {
                unsigned int* dst = ebuf + bb[b] + goff[(size_t)blk * B + b];
                for (int k = lane; k < cnt; k += 64) dst[k] = buf[lo + k];
            }
        }
    } else {  // adversarial-size fallback: direct scatter
        for (int i = tid; i < B; i += 512)
            lf[i] = bb[i] + goff[(size_t)blk * B + i];
        __syncthreads();
        for (int i = s0 + tid; i < s1; i += 512) {
            const int d = edge_val(edges, (size_t)E + i, is64);
            const int s = edge_val(edges, (size_t)i, is64);
            const int pos = atomicAdd(&lf[d >> 8], 1);
            ebuf[pos] = ((unsigned int)s << 8) | (unsigned int)(d & 255);
        }
    }
}

// Per-bucket counting sort -> col_src CSR + row_ptr + dinv.
__global__ __launch_bounds__(512) void bucket_csr(
    const unsigned int* __restrict__ ebuf, const int* __restrict__ bbase,
    int* __restrict__ row_ptr, float* __restrict__ dinv,
    int* __restrict__ col_src, int n) {
    __shared__ int hist[256];
    __shared__ int scn[256];
    __shared__ int fill[256];
    const int tid = threadIdx.x;
    const int b = blockIdx.x;
    if (tid < 256) hist[tid] = 0;
    __syncthreads();
    const int base = bbase[b];
    const int m = bbase[b + 1] - base;
    const unsigned int* eb = ebuf + base;
    for (int i = tid; i < m; i += 512) atomicAdd(&hist[eb[i] & 255u], 1);
    __syncthreads();
    if (tid < 256) scn[tid] = hist[tid];
    __syncthreads();
    for (int off = 1; off < 256; off <<= 1) {
        int val = 0;
        if (tid < 256 && tid >= off) val = scn[tid - off];
        __syncthreads();
        if (tid < 256) scn[tid] += val;
        __syncthreads();
    }
    if (tid < 256) {
        const int excl = scn[tid] - hist[tid];
        fill[tid] = excl;
        const int v = b * 256 + tid;
        if (v < n) {
            row_ptr[v] = base + excl;
            dinv[v] = rsqrtf((float)hist[tid] + 1.0f);
        }
    }
    __syncthreads();
    for (int i = tid; i < m; i += 512) {
        const unsigned int e = eb[i];
        const int p = atomicAdd(&fill[e & 255u], 1);
        col_src[base + p] = (int)(e >> 8);
    }
}

// GEMM1 (MFMA): hs1f8[v][c] = fp8((x@W1)[v][c] * dinv[v]),  256 -> 64.
// x loads nontemporal: pure 102MB stream, keep L2 for the gather table.
__global__ __launch_bounds__(256) void gemm1_kernel(
    const float* __restrict__ x, const float* __restrict__ W1,
    const float* __restrict__ dinv, unsigned char* __restrict__ hs1f8, int n) {
    __shared__ unsigned short wt[64 * 264];  // [col][k], 33792 B
    const int tid = threadIdx.x;
    for (int i = tid; i < 4096; i += 256) {
        const int k = i >> 4;
        const int c0 = (i & 15) * 4;
        const float4 w = *((const float4*)W1 + i);
        wt[(c0 + 0) * 264 + k] = f2bf(w.x);
        wt[(c0 + 1) * 264 + k] = f2bf(w.y);
        wt[(c0 + 2) * 264 + k] = f2bf(w.z);
        wt[(c0 + 3) * 264 + k] = f2bf(w.w);
    }
    __syncthreads();

    const int lane = tid & 63;
    const int wid = tid >> 6;
    const int row0 = blockIdx.x * 64 + wid * 16;
    const int rr = lane & 15;
    const int kh = lane >> 4;

    union FragU { bf16x8 v; unsigned short u[8]; };
    bf16x8 af[8];
    {
        int r = row0 + rr;
        if (r >= n) r = n - 1;
        const float* xr = x + (size_t)r * 256 + kh * 8;
#pragma unroll
        for (int ks = 0; ks < 8; ++ks) {
            const nf4 p0 = __builtin_nontemporal_load((const nf4*)(xr + ks * 32));
            const nf4 p1 = __builtin_nontemporal_load((const nf4*)(xr + ks * 32 + 4));
            FragU f;
            f.u[0] = f2bf(p0[0]); f.u[1] = f2bf(p0[1]);
            f.u[2] = f2bf(p0[2]); f.u[3] = f2bf(p0[3]);
            f.u[4] = f2bf(p1[0]); f.u[5] = f2bf(p1[1]);
            f.u[6] = f2bf(p1[2]); f.u[7] = f2bf(p1[3]);
            af[ks] = f.v;
        }
    }
    f32x4 acc[4];
#pragma unroll
    for (int ct = 0; ct < 4; ++ct) acc[ct] = (f32x4){0.f, 0.f, 0.f, 0.f};
#pragma unroll
    for (int ct = 0; ct < 4; ++ct) {
        const unsigned short* wcol = wt + (ct * 16 + rr) * 264 + kh * 8;
#pragma unroll
        for (int ks = 0; ks < 8; ++ks) {
            const bf16x8 bf = *(const bf16x8*)(wcol + ks * 32);
            acc[ct] = __builtin_amdgcn_mfma_f32_16x16x32_bf16(af[ks], bf, acc[ct], 0, 0, 0);
        }
    }
#pragma unroll
    for (int j = 0; j < 4; ++j) {
        const int gr = row0 + kh * 4 + j;
        if (gr < n) {
            const float dv = dinv[gr];
#pragma unroll
            for (int ct = 0; ct < 4; ++ct)
                hs1f8[(size_t)gr * 64 + ct * 16 + rr] = f32_to_fp8(acc[ct][j] * dv);
        }
    }
}

// AGG1 + fused GEMM2: 16-lane group per node (4 nodes/wave). Lane q loads
// 4 fp8 cols (4B) -> 16 lanes cover a full 64B row; 16 rows in flight per
// group step. Width-16 shfl reduce for the fused res@W2.
__global__ __launch_bounds__(256) void agg1_kernel(
    const int* __restrict__ row_ptr, const int* __restrict__ col_src,
    const unsigned char* __restrict__ hs1f8, const float* __restrict__ dinv,
    const float* __restrict__ b1, const float* __restrict__ W2,
    float* __restrict__ hs2, int n) {
    const int tid = threadIdx.x;
    const int q = tid & 15;
    const int v = blockIdx.x * 16 + (tid >> 4);
    if (v >= n) return;
    const int rs = row_ptr[v];
    const int re = row_ptr[v + 1];
    float a0 = 0.f, a1 = 0.f, a2 = 0.f, a3 = 0.f;
    int e = rs;
    for (; e + 16 <= re; e += 16) {
        const int cs = col_src[e + q];
        unsigned int r[16];
#pragma unroll
        for (int j = 0; j < 16; ++j) {
            const int s = __shfl(cs, j, 16);
            r[j] = *(const unsigned int*)(hs1f8 + (size_t)s * 64 + q * 4);
        }
#pragma unroll
        for (int j = 0; j < 16; ++j) acc_fp8row(r[j], a0, a1, a2, a3);
    }
    const int rem = re - e;
    if (rem > 0) {
        const int cs = col_src[(q < rem) ? e + q : re - 1];
        for (int j = 0; j < rem; ++j) {
            const int s = __shfl(cs, j, 16);
            const unsigned int r = *(const unsigned int*)(hs1f8 + (size_t)s * 64 + q * 4);
            acc_fp8row(r, a0, a1, a2, a3);
        }
    }
    // self-term + bias + leaky
    float s0 = 0.f, s1 = 0.f, s2 = 0.f, s3 = 0.f;
    acc_fp8row(*(const unsigned int*)(hs1f8 + (size_t)v * 64 + q * 4), s0, s1, s2, s3);
    const float dv = dinv[v];
    const float4 bb = ((const float4*)b1)[q];
    float4 res;
    res.x = dv * (a0 + s0) + bb.x;
    res.y = dv * (a1 + s1) + bb.y;
    res.z = dv * (a2 + s2) + bb.z;
    res.w = dv * (a3 + s3) + bb.w;
    res.x = res.x > 0.f ? res.x : 0.01f * res.x;
    res.y = res.y > 0.f ? res.y : 0.01f * res.y;
    res.z = res.z > 0.f ? res.z : 0.01f * res.z;
    res.w = res.w > 0.f ? res.w : 0.01f * res.w;
    // fused gemm2: p = res . W2[4q..4q+3][:]; reduce over the 16 q-lanes
    const float4* W2v = (const float4*)W2;
    const float4 w0 = W2v[q * 4 + 0], w1 = W2v[q * 4 + 1];
    const float4 w2 = W2v[q * 4 + 2], w3 = W2v[q * 4 + 3];
    float4 p;
    p.x = res.x * w0.x + res.y * w1.x + res.z * w2.x + res.w * w3.x;
    p.y = res.x * w0.y + res.y * w1.y + res.z * w2.y + res.w * w3.y;
    p.z = res.x * w0.z + res.y * w1.z + res.z * w2.z + res.w * w3.z;
    p.w = res.x * w0.w + res.y * w1.w + res.z * w2.w + res.w * w3.w;
#pragma unroll
    for (int s = 1; s < 16; s <<= 1) {
        p.x += __shfl_xor(p.x, s, 16); p.y += __shfl_xor(p.y, s, 16);
        p.z += __shfl_xor(p.z, s, 16); p.w += __shfl_xor(p.w, s, 16);
    }
    if (q == 0) {
        float4 o; o.x = p.x * dv; o.y = p.y * dv; o.z = p.z * dv; o.w = p.w * dv;
        *(float4*)(hs2 + (size_t)v * 4) = o;
    }
}

// AGG2 + softmax: wave per node; lane -> (edge slot = lane>>2, col = lane&3)
__global__ __launch_bounds__(256) void agg2_kernel(
    const int* __restrict__ row_ptr, const int* __restrict__ col_src,
    const float* __restrict__ hs2, const float* __restrict__ dinv,
    const float* __restrict__ b2, float* __restrict__ out, int n) {
    const int lane = threadIdx.x & 63;
    int v = blockIdx.x * 4 + (threadIdx.x >> 6);
    v = __builtin_amdgcn_readfirstlane(v);
    if (v >= n) return;
    const int c = lane & 3;
    const int ei = lane >> 2;
    const int rs = row_ptr[v];
    const int re = row_ptr[v + 1];
    float acc = 0.f;
    for (int e0 = rs; e0 < re; e0 += 16) {
        const int e = e0 + ei;
        if (e < re) {
            const int s = col_src[e];
            acc += hs2[(size_t)s * 4 + c];
        }
    }
    acc += __shfl_xor(acc, 4);
    acc += __shfl_xor(acc, 8);
    acc += __shfl_xor(acc, 16);
    acc += __shfl_xor(acc, 32);
    const float val = dinv[v] * (acc + hs2[(size_t)v * 4 + c]) + b2[c];
    float m = fmaxf(val, __shfl_xor(val, 1));
    m = fmaxf(m, __shfl_xor(m, 2));
    const float ex = __expf(val - m);
    float s = ex + __shfl_xor(ex, 1);
    s += __shfl_xor(s, 2);
    if (lane < 4) out[(size_t)v * 4 + c] = ex / s;
}

extern "C" void kernel_launch(void* const* d_in, const int* in_sizes, int n_in,
                              void* d_out, int out_size, void* d_ws, size_t ws_size,
                              hipStream_t stream) {
    const float* x  = (const float*)d_in[0];
    const void*  ei = d_in[1];
    const float* W1 = (const float*)d_in[2];
    const float* b1 = (const float*)d_in[3];
    const float* W2 = (const float*)d_in[4];
    const float* b2 = (const float*)d_in[5];
    const int n = in_sizes[0] / 256;
    const int E = in_sizes[1] / 2;
    const int B = (n + 255) / 256;  // <= MAXB for n <= 131072

    char* ws = (char*)d_ws;
    size_t off = 0;
    auto alloc = [&](size_t bytes) -> void* {
        void* p = ws + off;
        off += (bytes + 255) & ~(size_t)255;
        return p;
    };
    int*   ghist   = (int*)alloc(sizeof(int) * (size_t)NB * B);
    int*   goff    = (int*)alloc(sizeof(int) * (size_t)NB * B);
    int*   bsum    = (int*)alloc(sizeof(int) * B);
    int*   bbase   = (int*)alloc(sizeof(int) * (B + 1));
    int*   row_ptr = (int*)alloc(sizeof(int) * (n + 1));
    int*   col_src = (int*)alloc(sizeof(int) * (size_t)E);
    float* dinv    = (float*)alloc(sizeof(float) * n);
    unsigned char* hs1f8 = (unsigned char*)alloc(sizeof(unsigned char) * (size_t)n * 64);
    float* hs2     = (float*)alloc(sizeof(float) * (size_t)n * 4);
    unsigned int* ebuf = (unsigned int*)alloc(sizeof(unsigned int) * (size_t)E);
    (void)n_in; (void)out_size; (void)ws_size;

    hist_pass<<<NB, 512, 0, stream>>>(ei, E, ghist, B);
    col_scan<<<B, NB, 0, stream>>>(ghist, goff, bsum, B);
    scatter_pass<<<NB, 512, 0, stream>>>(ei, E, ghist, goff, bsum, bbase, row_ptr, ebuf, n, B);
    bucket_csr<<<B, 512, 0, stream>>>(ebuf, bbase, row_ptr, dinv, col_src, n);
    gemm1_kernel<<<(n + 63) / 64, 256, 0, stream>>>(x, W1, dinv, hs1f8, n);
    agg1_kernel<<<(n + 15) / 16, 256, 0, stream>>>(row_ptr, col_src, hs1f8, dinv, b1, W2, hs2, n);
    agg2_kernel<<<(n + 3) / 4, 256, 0, stream>>>(row_ptr, col_src, hs2, dinv, b2, (float*)d_out, n);
}